// Round 11
// baseline (91947.528 us; speedup 1.0000x reference)
//
#include <hip/hip_runtime.h>
#include <math.h>

#define D 256
#define SEQ 1000
#define NB 32
#define PATCH 160
#define NL 6
#define M_TOTAL (NB * SEQ)   // 32000
#define G3 (3 * D)           // 768

typedef _Float16 h2f __attribute__((ext_vector_type(2)));

__device__ __forceinline__ float gelu_exact(float v) {
    return 0.5f * v * (1.0f + erff(v * 0.70710678118654752440f));
}

// Raw workgroup barrier: orders LDS (lgkmcnt) but does NOT drain vmcnt, so
// in-flight global stores (x writeback) cross steps without stalling.
// (Harness-verified in rounds 3, 6, 7, 9, 10.)
__device__ __forceinline__ void bar_lds() {
    asm volatile("s_waitcnt lgkmcnt(0)" ::: "memory");
    __builtin_amdgcn_s_barrier();
    asm volatile("" ::: "memory");
}

// ---------------------------------------------------------------------------
// Kernel 1: conv patchify GEMM + exact GELU + pos_emb add
// ---------------------------------------------------------------------------
__global__ __launch_bounds__(256) void conv_gelu_pos(
    const float* __restrict__ wav, const float* __restrict__ cw,
    const float* __restrict__ pos, float* __restrict__ x)
{
    __shared__ float As[64][33];
    __shared__ float Bs[32][65];
    const int m0 = blockIdx.x * 64;
    const int n0 = blockIdx.y * 64;
    const int tid = threadIdx.x;
    const int tx = tid & 15;      // 0..15 -> n
    const int ty = tid >> 4;      // 0..15 -> m
    float acc[4][4] = {};

    for (int kc = 0; kc < PATCH; kc += 32) {
        for (int p = 0; p < 8; ++p) {
            int mr = p * 8 + (tid >> 5);
            int kk = tid & 31;
            int m = m0 + mr;
            int b = m / SEQ, s = m % SEQ;
            As[mr][kk] = wav[(size_t)b * 160000 + (size_t)s * PATCH + kc + kk];
        }
        for (int p = 0; p < 8; ++p) {
            int kr = p * 4 + (tid >> 6);
            int nn = tid & 63;
            Bs[kr][nn] = cw[(size_t)(kc + kr) * D + n0 + nn];
        }
        __syncthreads();
        #pragma unroll
        for (int kk = 0; kk < 32; ++kk) {
            float a[4], bb[4];
            #pragma unroll
            for (int i = 0; i < 4; ++i) a[i] = As[ty * 4 + i][kk];
            #pragma unroll
            for (int j = 0; j < 4; ++j) bb[j] = Bs[kk][tx * 4 + j];
            #pragma unroll
            for (int i = 0; i < 4; ++i)
                #pragma unroll
                for (int j = 0; j < 4; ++j)
                    acc[i][j] = fmaf(a[i], bb[j], acc[i][j]);
        }
        __syncthreads();
    }
    #pragma unroll
    for (int i = 0; i < 4; ++i) {
        int m = m0 + ty * 4 + i;
        int s = m % SEQ;
        int n = n0 + tx * 4;
        float4 v;
        v.x = gelu_exact(acc[i][0]) + pos[(size_t)s * D + n + 0];
        v.y = gelu_exact(acc[i][1]) + pos[(size_t)s * D + n + 1];
        v.z = gelu_exact(acc[i][2]) + pos[(size_t)s * D + n + 2];
        v.w = gelu_exact(acc[i][3]) + pos[(size_t)s * D + n + 3];
        *(float4*)&x[(size_t)m * D + n] = v;
    }
}

// ---------------------------------------------------------------------------
// Kernel 2: per-row mean / rstd (LayerNorm stats). One wave per row.
// ---------------------------------------------------------------------------
__global__ __launch_bounds__(64) void row_stats(
    const float* __restrict__ x, float* __restrict__ st)
{
    const int m = blockIdx.x;
    const int t = threadIdx.x;
    const float* r = x + (size_t)m * D;
    float s = 0.f, q = 0.f;
    #pragma unroll
    for (int i = 0; i < 4; ++i) {
        float v = r[t + 64 * i];
        s += v;
        q += v * v;
    }
    #pragma unroll
    for (int o = 32; o > 0; o >>= 1) {
        s += __shfl_down(s, o);
        q += __shfl_down(q, o);
    }
    if (t == 0) {
        float mu = s * (1.f / 256.f);
        float var = q * (1.f / 256.f) - mu * mu;
        st[2 * m]     = mu;
        st[2 * m + 1] = rsqrtf(var + 1e-5f);
    }
}

// ---------------------------------------------------------------------------
// Kernel 3: fused LN + input-projection GEMM
// ---------------------------------------------------------------------------
__global__ __launch_bounds__(256) void ln_xp_gemm(
    const float* __restrict__ x, const float* __restrict__ st,
    const float* __restrict__ lnsc, const float* __restrict__ lnbi,
    const float* __restrict__ wih, const float* __restrict__ bih,
    float* __restrict__ xp)
{
    __shared__ float As[64][33];
    __shared__ float Bs[32][65];
    __shared__ float sc[D], bi[D];
    const int m0 = blockIdx.x * 64;
    const int n0 = blockIdx.y * 64;
    const int tid = threadIdx.x;
    const int tx = tid & 15;
    const int ty = tid >> 4;
    sc[tid] = lnsc[tid];
    bi[tid] = lnbi[tid];
    float acc[4][4] = {};

    for (int kc = 0; kc < D; kc += 32) {
        for (int p = 0; p < 8; ++p) {
            int mr = p * 8 + (tid >> 5);
            int kk = tid & 31;
            int m = m0 + mr;
            float mu = st[2 * m], rs = st[2 * m + 1];
            float v = x[(size_t)m * D + kc + kk];
            As[mr][kk] = (v - mu) * rs * sc[kc + kk] + bi[kc + kk];
        }
        for (int p = 0; p < 8; ++p) {
            int nr = p * 8 + (tid >> 5);
            int kk = tid & 31;
            Bs[kk][nr] = wih[(size_t)(n0 + nr) * D + kc + kk];
        }
        __syncthreads();
        #pragma unroll
        for (int kk = 0; kk < 32; ++kk) {
            float a[4], bb[4];
            #pragma unroll
            for (int i = 0; i < 4; ++i) a[i] = As[ty * 4 + i][kk];
            #pragma unroll
            for (int j = 0; j < 4; ++j) bb[j] = Bs[kk][tx * 4 + j];
            #pragma unroll
            for (int i = 0; i < 4; ++i)
                #pragma unroll
                for (int j = 0; j < 4; ++j)
                    acc[i][j] = fmaf(a[i], bb[j], acc[i][j]);
        }
        __syncthreads();
    }
    #pragma unroll
    for (int i = 0; i < 4; ++i) {
        int m = m0 + ty * 4 + i;
        int n = n0 + tx * 4;
        float4 v;
        v.x = acc[i][0] + bih[n + 0];
        v.y = acc[i][1] + bih[n + 1];
        v.z = acc[i][2] + bih[n + 2];
        v.w = acc[i][3] + bih[n + 3];
        *(float4*)&xp[(size_t)m * G3 + n] = v;
    }
}

// ---------------------------------------------------------------------------
// Kernel 4: pack w_hh fp32 -> fp16 pairs, laid out for coalesced per-thread
// register loads in the GRU kernel: word [kh][s][d] (u32 = 2 fp16) where
// s = gate*64 + j covers k = kh*128 + 2j, 2j+1 for output dim d.
// ---------------------------------------------------------------------------
__global__ __launch_bounds__(256) void pack_whh(
    const float* __restrict__ whh, unsigned int* __restrict__ wh16)
{
    const int b  = blockIdx.x;        // 0..383
    const int kh = b / 192;
    const int s  = b % 192;
    const int gi = s / 64;            // gate 0=r 1=z 2=n
    const int j  = s % 64;            // k-pair index
    const int d  = threadIdx.x;       // output dim
    const size_t row = (size_t)(gi * D + d) * D + kh * 128 + 2 * j;
    unsigned short lo = __builtin_bit_cast(unsigned short, (_Float16)whh[row]);
    unsigned short hi = __builtin_bit_cast(unsigned short, (_Float16)whh[row + 1]);
    wh16[(size_t)(kh * 192 + s) * 256 + d] = (unsigned int)lo | ((unsigned int)hi << 16);
}

// ---------------------------------------------------------------------------
// Kernel 5: GRU recurrence — SINGLE block per batch, register-resident fp16
// weights (float-typed containers), fp32 h state. NO cross-block exchange.
//
// Round-10 post-mortem: numerics PASSED (absmax 1.7e-3) but the single
// h2f[192] array went to SCRATCH (VGPR_Count=128, 15ms/dispatch). Fixes:
//   1. Array shape = r7's proven-resident shape: SIX float[32] arrays
//      (float containers for packed fp16 pairs; bit_cast to h2f only at
//      use). Identical declaration pattern to r1/r7/r9's fast arrays.
//   2. __launch_bounds__(512, 1): raises the arch-VGPR cap (empirically
//      128 with (512,2) in ALL prior rounds) to 256. Only 32 blocks exist
//      -> one per CU regardless; 8 waves/block = 2 waves/SIMD x 256 VGPR
//      = exactly the register file (m69). 192 weight words + ~40 working
//      fits in arch VGPRs outright.
// FMA via fmaf((float)p.x, hv.x, acc) -> clang fma-mix (v_fma_mix_f32
// reads fp16 halves in place); cvt-fallback still ~2.5x under round 9.
// Structure = proven khalf split + LDS reduce; 2 bar_lds/step; no atomics.
// ---------------------------------------------------------------------------
__global__ __launch_bounds__(512, 1) void gru_scan_regs(
    const float* __restrict__ xp, const unsigned int* __restrict__ wh16,
    const float* __restrict__ bhh, float* __restrict__ x)
{
    __shared__ float h_lds[D];          // fp32 h(t)
    __shared__ float pr[3][D];          // khalf1 partials [gate][d]
    const int tid   = threadIdx.x;
    const int d     = tid & 255;
    const int khalf = tid >> 8;         // 0 or 1 (wave-uniform)
    const int batch = blockIdx.x;

    // --- resident weights: 6 x 32 float-containers (= 384 fp16), coalesced -
    // gate g, pair j (k = khalf*128 + 2j, 2j+1): j<32 -> A[j], j>=32 -> B[j-32]
    float wrA[32], wrB[32], wzA[32], wzB[32], wnA[32], wnB[32];
    {
        const unsigned int* wb = wh16 + (size_t)khalf * 192 * 256 + d;
        #pragma unroll
        for (int j = 0; j < 32; ++j) wrA[j] = __uint_as_float(wb[(size_t)(0 * 64 + j) * 256]);
        #pragma unroll
        for (int j = 0; j < 32; ++j) wrB[j] = __uint_as_float(wb[(size_t)(0 * 64 + 32 + j) * 256]);
        #pragma unroll
        for (int j = 0; j < 32; ++j) wzA[j] = __uint_as_float(wb[(size_t)(1 * 64 + j) * 256]);
        #pragma unroll
        for (int j = 0; j < 32; ++j) wzB[j] = __uint_as_float(wb[(size_t)(1 * 64 + 32 + j) * 256]);
        #pragma unroll
        for (int j = 0; j < 32; ++j) wnA[j] = __uint_as_float(wb[(size_t)(2 * 64 + j) * 256]);
        #pragma unroll
        for (int j = 0; j < 32; ++j) wnB[j] = __uint_as_float(wb[(size_t)(2 * 64 + 32 + j) * 256]);
    }
    const float bh_r = bhh[d];
    const float bh_z = bhh[D + d];
    const float bh_n = bhh[2 * D + d];

    const float* xpb = xp + (size_t)batch * SEQ * G3;
    float* xb = x + (size_t)batch * SEQ * D;

    if (tid < D) h_lds[tid] = 0.f;
    __syncthreads();

    const float* hb = &h_lds[khalf * 128];
    for (int t = 0; t < SEQ; ++t) {
        // issue xp + residual loads early; latency hides under the FMA phase
        float xr = 0.f, xz = 0.f, xn_ = 0.f, xold = 0.f;
        if (khalf == 0) {
            const float* xpt = xpb + (size_t)t * G3;
            xr   = xpt[d];
            xz   = xpt[D + d];
            xn_  = xpt[2 * D + d];
            xold = xb[(size_t)t * D + d];
        }

        // --- FMA phase: 384 mixed-precision MACs against resident fp16 -----
        float ar = 0.f, az = 0.f, an = 0.f;
        #pragma unroll
        for (int q = 0; q < 16; ++q) {        // k = 4q .. 4q+3  (pairs 2q,2q+1)
            float4 hv = *(const float4*)(hb + 4 * q);   // uniform bcast
            h2f r0 = __builtin_bit_cast(h2f, wrA[2*q]), r1 = __builtin_bit_cast(h2f, wrA[2*q+1]);
            h2f z0 = __builtin_bit_cast(h2f, wzA[2*q]), z1 = __builtin_bit_cast(h2f, wzA[2*q+1]);
            h2f n0 = __builtin_bit_cast(h2f, wnA[2*q]), n1 = __builtin_bit_cast(h2f, wnA[2*q+1]);
            ar = fmaf((float)r0.x, hv.x, ar); ar = fmaf((float)r0.y, hv.y, ar);
            ar = fmaf((float)r1.x, hv.z, ar); ar = fmaf((float)r1.y, hv.w, ar);
            az = fmaf((float)z0.x, hv.x, az); az = fmaf((float)z0.y, hv.y, az);
            az = fmaf((float)z1.x, hv.z, az); az = fmaf((float)z1.y, hv.w, az);
            an = fmaf((float)n0.x, hv.x, an); an = fmaf((float)n0.y, hv.y, an);
            an = fmaf((float)n1.x, hv.z, an); an = fmaf((float)n1.y, hv.w, an);
        }
        #pragma unroll
        for (int q = 0; q < 16; ++q) {        // k = 64+4q .. 64+4q+3
            float4 hv = *(const float4*)(hb + 64 + 4 * q);
            h2f r0 = __builtin_bit_cast(h2f, wrB[2*q]), r1 = __builtin_bit_cast(h2f, wrB[2*q+1]);
            h2f z0 = __builtin_bit_cast(h2f, wzB[2*q]), z1 = __builtin_bit_cast(h2f, wzB[2*q+1]);
            h2f n0 = __builtin_bit_cast(h2f, wnB[2*q]), n1 = __builtin_bit_cast(h2f, wnB[2*q+1]);
            ar = fmaf((float)r0.x, hv.x, ar); ar = fmaf((float)r0.y, hv.y, ar);
            ar = fmaf((float)r1.x, hv.z, ar); ar = fmaf((float)r1.y, hv.w, ar);
            az = fmaf((float)z0.x, hv.x, az); az = fmaf((float)z0.y, hv.y, az);
            az = fmaf((float)z1.x, hv.z, az); az = fmaf((float)z1.y, hv.w, az);
            an = fmaf((float)n0.x, hv.x, an); an = fmaf((float)n0.y, hv.y, an);
            an = fmaf((float)n1.x, hv.z, an); an = fmaf((float)n1.y, hv.w, an);
        }
        if (khalf) { pr[0][d] = ar; pr[1][d] = az; pr[2][d] = an; }
        bar_lds();

        // --- finalize: combine (own lo-K + peer hi-K), gates, update -------
        if (khalf == 0) {
            float gr = xr + ar + pr[0][d] + bh_r;
            float gz = xz + az + pr[1][d] + bh_z;
            float gn =      an + pr[2][d] + bh_n;
            float r = 1.f / (1.f + expf(-gr));
            float z = 1.f / (1.f + expf(-gz));
            float n = tanhf(xn_ + r * gn);
            float hnew = (1.f - z) * n + z * h_lds[d];
            h_lds[d] = hnew;
            xb[(size_t)t * D + d] = xold + hnew;
        }
        bar_lds();
    }
}

// ---------------------------------------------------------------------------
// Kernel 6: final LN + mean-pool over sequence
// ---------------------------------------------------------------------------
__global__ __launch_bounds__(256) void pool_ln(
    const float* __restrict__ x, const float* __restrict__ st,
    const float* __restrict__ fsc, const float* __restrict__ fbi,
    float* __restrict__ emb)
{
    const int b = blockIdx.x;
    const int d = threadIdx.x;
    float acc = 0.f;
    for (int s = 0; s < SEQ; ++s) {
        int m = b * SEQ + s;
        acc += (x[(size_t)m * D + d] - st[2 * m]) * st[2 * m + 1];
    }
    emb[b * D + d] = (acc * (1.f / (float)SEQ)) * fsc[d] + fbi[d];
}

// ---------------------------------------------------------------------------
// Kernel 7: classification head (tiny). Single block.
// ---------------------------------------------------------------------------
__global__ __launch_bounds__(256) void head_mlp(
    const float* __restrict__ emb, const float* __restrict__ w1,
    const float* __restrict__ b1, const float* __restrict__ w2,
    const float* __restrict__ b2, float* __restrict__ out)
{
    __shared__ float es[NB][D + 1];
    __shared__ float h1[NB][128 + 1];
    const int t = threadIdx.x;
    for (int i = t; i < NB * D; i += 256) es[i / D][i % D] = emb[i];
    __syncthreads();
    for (int i = t; i < NB * 128; i += 256) {
        int bb = i / 128, j = i % 128;
        float a = b1[j];
        for (int k = 0; k < D; ++k) a = fmaf(es[bb][k], w1[(size_t)k * 128 + j], a);
        h1[bb][j] = gelu_exact(a);
    }
    __syncthreads();
    for (int i = t; i < NB * 8; i += 256) {
        int bb = i / 8, c = i % 8;
        float a = b2[c];
        for (int k = 0; k < 128; ++k) a = fmaf(h1[bb][k], w2[(size_t)k * 8 + c], a);
        out[i] = a;
    }
}

// ---------------------------------------------------------------------------
extern "C" void kernel_launch(void* const* d_in, const int* in_sizes, int n_in,
                              void* d_out, int out_size, void* d_ws, size_t ws_size,
                              hipStream_t stream)
{
    const float* wav  = (const float*)d_in[0];
    const float* cw   = (const float*)d_in[1];
    const float* pos  = (const float*)d_in[2];
    const float* lnsc = (const float*)d_in[3];
    const float* lnbi = (const float*)d_in[4];
    const float* wih  = (const float*)d_in[5];
    const float* whh  = (const float*)d_in[6];
    const float* bih  = (const float*)d_in[7];
    const float* bhh  = (const float*)d_in[8];
    const float* fsc  = (const float*)d_in[9];
    const float* fbi  = (const float*)d_in[10];
    const float* hw1  = (const float*)d_in[11];
    const float* hb1  = (const float*)d_in[12];
    const float* hw2  = (const float*)d_in[13];
    const float* hb2  = (const float*)d_in[14];

    float* ws    = (float*)d_ws;
    float* x     = ws;                        // 8,192,000 f
    float* xp    = x + (size_t)M_TOTAL * D;   // 24,576,000 f
    float* st    = xp + (size_t)M_TOTAL * G3; // 64,000 f
    unsigned int* wh16 = (unsigned int*)(st + 2 * M_TOTAL); // 98,304 u32
    float* emb   = (float*)(wh16 + 98304);    // 8,192 f

    conv_gelu_pos<<<dim3(M_TOTAL / 64, D / 64), 256, 0, stream>>>(wav, cw, pos, x);

    for (int l = 0; l < NL; ++l) {
        row_stats<<<M_TOTAL, 64, 0, stream>>>(x, st);
        ln_xp_gemm<<<dim3(M_TOTAL / 64, G3 / 64), 256, 0, stream>>>(
            x, st, lnsc + (size_t)l * D, lnbi + (size_t)l * D,
            wih + (size_t)l * G3 * D, bih + (size_t)l * G3, xp);
        pack_whh<<<384, 256, 0, stream>>>(whh + (size_t)l * G3 * D, wh16);
        gru_scan_regs<<<NB, 512, 0, stream>>>(
            xp, wh16, bhh + (size_t)l * G3, x);
    }

    row_stats<<<M_TOTAL, 64, 0, stream>>>(x, st);
    pool_ln<<<NB, D, 0, stream>>>(x, st, fsc, fbi, emb);
    head_mlp<<<1, 256, 0, stream>>>(emb, hw1, hb1, hw2, hb2, (float*)d_out);
}

// Round 12
// 14739.243 us; speedup vs baseline: 6.2383x; 6.2383x over previous
//
#include <hip/hip_runtime.h>
#include <math.h>

#define D 256
#define SEQ 1000
#define NB 32
#define PATCH 160
#define NL 6
#define M_TOTAL (NB * SEQ)   // 32000
#define G3 (3 * D)           // 768

__device__ __forceinline__ float gelu_exact(float v) {
    return 0.5f * v * (1.0f + erff(v * 0.70710678118654752440f));
}

// Raw workgroup barrier: orders LDS (lgkmcnt) but does NOT drain vmcnt.
// (Harness-verified in rounds 3, 6, 7, 9, 10, 11.)
__device__ __forceinline__ void bar_lds() {
    asm volatile("s_waitcnt lgkmcnt(0)" ::: "memory");
    __builtin_amdgcn_s_barrier();
    asm volatile("" ::: "memory");
}

// Mixed-precision FMA: acc += f32(fp16 half of w) * h.  The fp16 operand is
// read IN PLACE from the packed word (op_sel_hi[0]=1) — no fpext exists in
// the IR, so LICM cannot hoist 384 conversions out of the t-loop (the r10/
// r11 scratch disaster). Asm is opaque -> containers stay 192 words/thread.
#define FMLO(acc, w, h) asm("v_fma_mix_f32 %0, %1, %2, %0 op_sel_hi:[1,0,0]" \
                            : "+v"(acc) : "v"(w), "v"(h))
#define FMHI(acc, w, h) asm("v_fma_mix_f32 %0, %1, %2, %0 op_sel:[1,0,0] op_sel_hi:[1,0,0]" \
                            : "+v"(acc) : "v"(w), "v"(h))

// ---------------------------------------------------------------------------
// Kernel 1: conv patchify GEMM + exact GELU + pos_emb add
// ---------------------------------------------------------------------------
__global__ __launch_bounds__(256) void conv_gelu_pos(
    const float* __restrict__ wav, const float* __restrict__ cw,
    const float* __restrict__ pos, float* __restrict__ x)
{
    __shared__ float As[64][33];
    __shared__ float Bs[32][65];
    const int m0 = blockIdx.x * 64;
    const int n0 = blockIdx.y * 64;
    const int tid = threadIdx.x;
    const int tx = tid & 15;      // 0..15 -> n
    const int ty = tid >> 4;      // 0..15 -> m
    float acc[4][4] = {};

    for (int kc = 0; kc < PATCH; kc += 32) {
        for (int p = 0; p < 8; ++p) {
            int mr = p * 8 + (tid >> 5);
            int kk = tid & 31;
            int m = m0 + mr;
            int b = m / SEQ, s = m % SEQ;
            As[mr][kk] = wav[(size_t)b * 160000 + (size_t)s * PATCH + kc + kk];
        }
        for (int p = 0; p < 8; ++p) {
            int kr = p * 4 + (tid >> 6);
            int nn = tid & 63;
            Bs[kr][nn] = cw[(size_t)(kc + kr) * D + n0 + nn];
        }
        __syncthreads();
        #pragma unroll
        for (int kk = 0; kk < 32; ++kk) {
            float a[4], bb[4];
            #pragma unroll
            for (int i = 0; i < 4; ++i) a[i] = As[ty * 4 + i][kk];
            #pragma unroll
            for (int j = 0; j < 4; ++j) bb[j] = Bs[kk][tx * 4 + j];
            #pragma unroll
            for (int i = 0; i < 4; ++i)
                #pragma unroll
                for (int j = 0; j < 4; ++j)
                    acc[i][j] = fmaf(a[i], bb[j], acc[i][j]);
        }
        __syncthreads();
    }
    #pragma unroll
    for (int i = 0; i < 4; ++i) {
        int m = m0 + ty * 4 + i;
        int s = m % SEQ;
        int n = n0 + tx * 4;
        float4 v;
        v.x = gelu_exact(acc[i][0]) + pos[(size_t)s * D + n + 0];
        v.y = gelu_exact(acc[i][1]) + pos[(size_t)s * D + n + 1];
        v.z = gelu_exact(acc[i][2]) + pos[(size_t)s * D + n + 2];
        v.w = gelu_exact(acc[i][3]) + pos[(size_t)s * D + n + 3];
        *(float4*)&x[(size_t)m * D + n] = v;
    }
}

// ---------------------------------------------------------------------------
// Kernel 2: per-row mean / rstd (LayerNorm stats). One wave per row.
// ---------------------------------------------------------------------------
__global__ __launch_bounds__(64) void row_stats(
    const float* __restrict__ x, float* __restrict__ st)
{
    const int m = blockIdx.x;
    const int t = threadIdx.x;
    const float* r = x + (size_t)m * D;
    float s = 0.f, q = 0.f;
    #pragma unroll
    for (int i = 0; i < 4; ++i) {
        float v = r[t + 64 * i];
        s += v;
        q += v * v;
    }
    #pragma unroll
    for (int o = 32; o > 0; o >>= 1) {
        s += __shfl_down(s, o);
        q += __shfl_down(q, o);
    }
    if (t == 0) {
        float mu = s * (1.f / 256.f);
        float var = q * (1.f / 256.f) - mu * mu;
        st[2 * m]     = mu;
        st[2 * m + 1] = rsqrtf(var + 1e-5f);
    }
}

// ---------------------------------------------------------------------------
// Kernel 3: fused LN + input-projection GEMM
// ---------------------------------------------------------------------------
__global__ __launch_bounds__(256) void ln_xp_gemm(
    const float* __restrict__ x, const float* __restrict__ st,
    const float* __restrict__ lnsc, const float* __restrict__ lnbi,
    const float* __restrict__ wih, const float* __restrict__ bih,
    float* __restrict__ xp)
{
    __shared__ float As[64][33];
    __shared__ float Bs[32][65];
    __shared__ float sc[D], bi[D];
    const int m0 = blockIdx.x * 64;
    const int n0 = blockIdx.y * 64;
    const int tid = threadIdx.x;
    const int tx = tid & 15;
    const int ty = tid >> 4;
    sc[tid] = lnsc[tid];
    bi[tid] = lnbi[tid];
    float acc[4][4] = {};

    for (int kc = 0; kc < D; kc += 32) {
        for (int p = 0; p < 8; ++p) {
            int mr = p * 8 + (tid >> 5);
            int kk = tid & 31;
            int m = m0 + mr;
            float mu = st[2 * m], rs = st[2 * m + 1];
            float v = x[(size_t)m * D + kc + kk];
            As[mr][kk] = (v - mu) * rs * sc[kc + kk] + bi[kc + kk];
        }
        for (int p = 0; p < 8; ++p) {
            int nr = p * 8 + (tid >> 5);
            int kk = tid & 31;
            Bs[kk][nr] = wih[(size_t)(n0 + nr) * D + kc + kk];
        }
        __syncthreads();
        #pragma unroll
        for (int kk = 0; kk < 32; ++kk) {
            float a[4], bb[4];
            #pragma unroll
            for (int i = 0; i < 4; ++i) a[i] = As[ty * 4 + i][kk];
            #pragma unroll
            for (int j = 0; j < 4; ++j) bb[j] = Bs[kk][tx * 4 + j];
            #pragma unroll
            for (int i = 0; i < 4; ++i)
                #pragma unroll
                for (int j = 0; j < 4; ++j)
                    acc[i][j] = fmaf(a[i], bb[j], acc[i][j]);
        }
        __syncthreads();
    }
    #pragma unroll
    for (int i = 0; i < 4; ++i) {
        int m = m0 + ty * 4 + i;
        int n = n0 + tx * 4;
        float4 v;
        v.x = acc[i][0] + bih[n + 0];
        v.y = acc[i][1] + bih[n + 1];
        v.z = acc[i][2] + bih[n + 2];
        v.w = acc[i][3] + bih[n + 3];
        *(float4*)&xp[(size_t)m * G3 + n] = v;
    }
}

// ---------------------------------------------------------------------------
// Kernel 4: pack w_hh fp32 -> fp16 pairs, laid out for coalesced per-thread
// register loads in the GRU kernel: word [kh][s][d] (u32 = 2 fp16) where
// s = gate*64 + j covers k = kh*128 + 2j, 2j+1 for output dim d.
// ---------------------------------------------------------------------------
__global__ __launch_bounds__(256) void pack_whh(
    const float* __restrict__ whh, unsigned int* __restrict__ wh16)
{
    const int b  = blockIdx.x;        // 0..383
    const int kh = b / 192;
    const int s  = b % 192;
    const int gi = s / 64;            // gate 0=r 1=z 2=n
    const int j  = s % 64;            // k-pair index
    const int d  = threadIdx.x;       // output dim
    const size_t row = (size_t)(gi * D + d) * D + kh * 128 + 2 * j;
    unsigned short lo = __builtin_bit_cast(unsigned short, (_Float16)whh[row]);
    unsigned short hi = __builtin_bit_cast(unsigned short, (_Float16)whh[row + 1]);
    wh16[(size_t)(kh * 192 + s) * 256 + d] = (unsigned int)lo | ((unsigned int)hi << 16);
}

// ---------------------------------------------------------------------------
// Kernel 5: GRU recurrence — SINGLE block per batch, register-resident fp16
// weights consumed by inline-asm v_fma_mix_f32. NO cross-block exchange.
//
// Round-11 post-mortem: fmaf((float)w16, h, acc) carries a loop-invariant
// fpext -> LICM hoisted 384 conversions out of the t-loop -> ~580 live
// words -> scratch (VGPR=128, 45us/step). v_fma_mix_f32 reads the fp16
// half IN PLACE from the packed word: no fpext in the IR, nothing to
// hoist, containers stay 192 words/thread (the count r7 proved resident),
// consuming instruction count = 384/step (same shape as r7's schedule).
// Numerics identical to r10/r11 (both PASSED): exact f16->f32 promote
// inside the FMA, f32 accumulate.
// Structure = proven khalf split + LDS reduce; 2 bar_lds/step; no atomics.
// Step ~= 1536cy SIMD issue (2 waves x 384 x 2cy) + ~400 overhead.
// ---------------------------------------------------------------------------
__global__ __launch_bounds__(512, 1) void gru_scan_regs(
    const float* __restrict__ xp, const unsigned int* __restrict__ wh16,
    const float* __restrict__ bhh, float* __restrict__ x)
{
    __shared__ float h_lds[D];          // fp32 h(t)
    __shared__ float pr[3][D];          // khalf1 partials [gate][d]
    const int tid   = threadIdx.x;
    const int d     = tid & 255;
    const int khalf = tid >> 8;         // 0 or 1 (wave-uniform)
    const int batch = blockIdx.x;

    // --- resident weights: 6 x 32 float-containers (= 384 fp16), coalesced -
    // gate g, pair j (k = khalf*128 + 2j, 2j+1): j<32 -> A[j], j>=32 -> B[j-32]
    float wrA[32], wrB[32], wzA[32], wzB[32], wnA[32], wnB[32];
    {
        const unsigned int* wb = wh16 + (size_t)khalf * 192 * 256 + d;
        #pragma unroll
        for (int j = 0; j < 32; ++j) wrA[j] = __uint_as_float(wb[(size_t)(0 * 64 + j) * 256]);
        #pragma unroll
        for (int j = 0; j < 32; ++j) wrB[j] = __uint_as_float(wb[(size_t)(0 * 64 + 32 + j) * 256]);
        #pragma unroll
        for (int j = 0; j < 32; ++j) wzA[j] = __uint_as_float(wb[(size_t)(1 * 64 + j) * 256]);
        #pragma unroll
        for (int j = 0; j < 32; ++j) wzB[j] = __uint_as_float(wb[(size_t)(1 * 64 + 32 + j) * 256]);
        #pragma unroll
        for (int j = 0; j < 32; ++j) wnA[j] = __uint_as_float(wb[(size_t)(2 * 64 + j) * 256]);
        #pragma unroll
        for (int j = 0; j < 32; ++j) wnB[j] = __uint_as_float(wb[(size_t)(2 * 64 + 32 + j) * 256]);
    }
    const float bh_r = bhh[d];
    const float bh_z = bhh[D + d];
    const float bh_n = bhh[2 * D + d];

    const float* xpb = xp + (size_t)batch * SEQ * G3;
    float* xb = x + (size_t)batch * SEQ * D;

    if (tid < D) h_lds[tid] = 0.f;
    __syncthreads();

    const float* hb = &h_lds[khalf * 128];
    for (int t = 0; t < SEQ; ++t) {
        // issue xp + residual loads early; latency hides under the FMA phase
        float xr = 0.f, xz = 0.f, xn_ = 0.f, xold = 0.f;
        if (khalf == 0) {
            const float* xpt = xpb + (size_t)t * G3;
            xr   = xpt[d];
            xz   = xpt[D + d];
            xn_  = xpt[2 * D + d];
            xold = xb[(size_t)t * D + d];
        }

        // --- FMA phase: 384 v_fma_mix_f32 against resident packed fp16 -----
        float ar = 0.f, az = 0.f, an = 0.f;
        #pragma unroll
        for (int q = 0; q < 16; ++q) {        // k = 4q .. 4q+3 (pairs 2q, 2q+1)
            float4 hv = *(const float4*)(hb + 4 * q);   // uniform bcast
            FMLO(ar, wrA[2*q],   hv.x); FMHI(ar, wrA[2*q],   hv.y);
            FMLO(ar, wrA[2*q+1], hv.z); FMHI(ar, wrA[2*q+1], hv.w);
            FMLO(az, wzA[2*q],   hv.x); FMHI(az, wzA[2*q],   hv.y);
            FMLO(az, wzA[2*q+1], hv.z); FMHI(az, wzA[2*q+1], hv.w);
            FMLO(an, wnA[2*q],   hv.x); FMHI(an, wnA[2*q],   hv.y);
            FMLO(an, wnA[2*q+1], hv.z); FMHI(an, wnA[2*q+1], hv.w);
        }
        #pragma unroll
        for (int q = 0; q < 16; ++q) {        // k = 64+4q .. 64+4q+3
            float4 hv = *(const float4*)(hb + 64 + 4 * q);
            FMLO(ar, wrB[2*q],   hv.x); FMHI(ar, wrB[2*q],   hv.y);
            FMLO(ar, wrB[2*q+1], hv.z); FMHI(ar, wrB[2*q+1], hv.w);
            FMLO(az, wzB[2*q],   hv.x); FMHI(az, wzB[2*q],   hv.y);
            FMLO(az, wzB[2*q+1], hv.z); FMHI(az, wzB[2*q+1], hv.w);
            FMLO(an, wnB[2*q],   hv.x); FMHI(an, wnB[2*q],   hv.y);
            FMLO(an, wnB[2*q+1], hv.z); FMHI(an, wnB[2*q+1], hv.w);
        }
        if (khalf) { pr[0][d] = ar; pr[1][d] = az; pr[2][d] = an; }
        bar_lds();

        // --- finalize: combine (own lo-K + peer hi-K), gates, update -------
        if (khalf == 0) {
            float gr = xr + ar + pr[0][d] + bh_r;
            float gz = xz + az + pr[1][d] + bh_z;
            float gn =      an + pr[2][d] + bh_n;
            float r = 1.f / (1.f + expf(-gr));
            float z = 1.f / (1.f + expf(-gz));
            float n = tanhf(xn_ + r * gn);
            float hnew = (1.f - z) * n + z * h_lds[d];
            h_lds[d] = hnew;
            xb[(size_t)t * D + d] = xold + hnew;
        }
        bar_lds();
    }
}

// ---------------------------------------------------------------------------
// Kernel 6: final LN + mean-pool over sequence
// ---------------------------------------------------------------------------
__global__ __launch_bounds__(256) void pool_ln(
    const float* __restrict__ x, const float* __restrict__ st,
    const float* __restrict__ fsc, const float* __restrict__ fbi,
    float* __restrict__ emb)
{
    const int b = blockIdx.x;
    const int d = threadIdx.x;
    float acc = 0.f;
    for (int s = 0; s < SEQ; ++s) {
        int m = b * SEQ + s;
        acc += (x[(size_t)m * D + d] - st[2 * m]) * st[2 * m + 1];
    }
    emb[b * D + d] = (acc * (1.f / (float)SEQ)) * fsc[d] + fbi[d];
}

// ---------------------------------------------------------------------------
// Kernel 7: classification head (tiny). Single block.
// ---------------------------------------------------------------------------
__global__ __launch_bounds__(256) void head_mlp(
    const float* __restrict__ emb, const float* __restrict__ w1,
    const float* __restrict__ b1, const float* __restrict__ w2,
    const float* __restrict__ b2, float* __restrict__ out)
{
    __shared__ float es[NB][D + 1];
    __shared__ float h1[NB][128 + 1];
    const int t = threadIdx.x;
    for (int i = t; i < NB * D; i += 256) es[i / D][i % D] = emb[i];
    __syncthreads();
    for (int i = t; i < NB * 128; i += 256) {
        int bb = i / 128, j = i % 128;
        float a = b1[j];
        for (int k = 0; k < D; ++k) a = fmaf(es[bb][k], w1[(size_t)k * 128 + j], a);
        h1[bb][j] = gelu_exact(a);
    }
    __syncthreads();
    for (int i = t; i < NB * 8; i += 256) {
        int bb = i / 8, c = i % 8;
        float a = b2[c];
        for (int k = 0; k < 128; ++k) a = fmaf(h1[bb][k], w2[(size_t)k * 8 + c], a);
        out[i] = a;
    }
}

// ---------------------------------------------------------------------------
extern "C" void kernel_launch(void* const* d_in, const int* in_sizes, int n_in,
                              void* d_out, int out_size, void* d_ws, size_t ws_size,
                              hipStream_t stream)
{
    const float* wav  = (const float*)d_in[0];
    const float* cw   = (const float*)d_in[1];
    const float* pos  = (const float*)d_in[2];
    const float* lnsc = (const float*)d_in[3];
    const float* lnbi = (const float*)d_in[4];
    const float* wih  = (const float*)d_in[5];
    const float* whh  = (const float*)d_in[6];
    const float* bih  = (const float*)d_in[7];
    const float* bhh  = (const float*)d_in[8];
    const float* fsc  = (const float*)d_in[9];
    const float* fbi  = (const float*)d_in[10];
    const float* hw1  = (const float*)d_in[11];
    const float* hb1  = (const float*)d_in[12];
    const float* hw2  = (const float*)d_in[13];
    const float* hb2  = (const float*)d_in[14];

    float* ws    = (float*)d_ws;
    float* x     = ws;                        // 8,192,000 f
    float* xp    = x + (size_t)M_TOTAL * D;   // 24,576,000 f
    float* st    = xp + (size_t)M_TOTAL * G3; // 64,000 f
    unsigned int* wh16 = (unsigned int*)(st + 2 * M_TOTAL); // 98,304 u32
    float* emb   = (float*)(wh16 + 98304);    // 8,192 f

    conv_gelu_pos<<<dim3(M_TOTAL / 64, D / 64), 256, 0, stream>>>(wav, cw, pos, x);

    for (int l = 0; l < NL; ++l) {
        row_stats<<<M_TOTAL, 64, 0, stream>>>(x, st);
        ln_xp_gemm<<<dim3(M_TOTAL / 64, G3 / 64), 256, 0, stream>>>(
            x, st, lnsc + (size_t)l * D, lnbi + (size_t)l * D,
            wih + (size_t)l * G3 * D, bih + (size_t)l * G3, xp);
        pack_whh<<<384, 256, 0, stream>>>(whh + (size_t)l * G3 * D, wh16);
        gru_scan_regs<<<NB, 512, 0, stream>>>(
            xp, wh16, bhh + (size_t)l * G3, x);
    }

    row_stats<<<M_TOTAL, 64, 0, stream>>>(x, st);
    pool_ln<<<NB, D, 0, stream>>>(x, st, fsc, fbi, emb);
    head_mlp<<<1, 256, 0, stream>>>(emb, hw1, hb1, hw2, hb2, (float*)d_out);
}

// Round 13
// 9837.237 us; speedup vs baseline: 9.3469x; 1.4983x over previous
//
#include <hip/hip_runtime.h>
#include <math.h>

#define D 256
#define SEQ 1000
#define NB 32
#define PATCH 160
#define NL 6
#define M_TOTAL (NB * SEQ)   // 32000
#define G3 (3 * D)           // 768

__device__ __forceinline__ float gelu_exact(float v) {
    return 0.5f * v * (1.0f + erff(v * 0.70710678118654752440f));
}

// Raw workgroup barrier: orders LDS (lgkmcnt) but does NOT drain vmcnt.
// (Harness-verified in rounds 3, 6, 7, 9, 10, 11, 12.)
__device__ __forceinline__ void bar_lds() {
    asm volatile("s_waitcnt lgkmcnt(0)" ::: "memory");
    __builtin_amdgcn_s_barrier();
    asm volatile("" ::: "memory");
}

// Packed dot2: acc += w.lo16*h.lo16 + w.hi16*h.hi16 (fp16 mul, fp32 accum).
// One instruction consumes a whole packed container word -> per container
// per step: worst 1 accvgpr_read + 1 dot2 (vs r12's 1 move + 2 fma_mix).
// Opaque asm = no fpext in IR = nothing for LICM to hoist (r10/r11 lesson).
#define DOT(acc, w, h) asm("v_dot2_f32_f16 %0, %1, %2, %0" \
                           : "+v"(acc) : "v"(w), "v"(h))

// ---------------------------------------------------------------------------
// Kernel 1: conv patchify GEMM + exact GELU + pos_emb add
// ---------------------------------------------------------------------------
__global__ __launch_bounds__(256) void conv_gelu_pos(
    const float* __restrict__ wav, const float* __restrict__ cw,
    const float* __restrict__ pos, float* __restrict__ x)
{
    __shared__ float As[64][33];
    __shared__ float Bs[32][65];
    const int m0 = blockIdx.x * 64;
    const int n0 = blockIdx.y * 64;
    const int tid = threadIdx.x;
    const int tx = tid & 15;      // 0..15 -> n
    const int ty = tid >> 4;      // 0..15 -> m
    float acc[4][4] = {};

    for (int kc = 0; kc < PATCH; kc += 32) {
        for (int p = 0; p < 8; ++p) {
            int mr = p * 8 + (tid >> 5);
            int kk = tid & 31;
            int m = m0 + mr;
            int b = m / SEQ, s = m % SEQ;
            As[mr][kk] = wav[(size_t)b * 160000 + (size_t)s * PATCH + kc + kk];
        }
        for (int p = 0; p < 8; ++p) {
            int kr = p * 4 + (tid >> 6);
            int nn = tid & 63;
            Bs[kr][nn] = cw[(size_t)(kc + kr) * D + n0 + nn];
        }
        __syncthreads();
        #pragma unroll
        for (int kk = 0; kk < 32; ++kk) {
            float a[4], bb[4];
            #pragma unroll
            for (int i = 0; i < 4; ++i) a[i] = As[ty * 4 + i][kk];
            #pragma unroll
            for (int j = 0; j < 4; ++j) bb[j] = Bs[kk][tx * 4 + j];
            #pragma unroll
            for (int i = 0; i < 4; ++i)
                #pragma unroll
                for (int j = 0; j < 4; ++j)
                    acc[i][j] = fmaf(a[i], bb[j], acc[i][j]);
        }
        __syncthreads();
    }
    #pragma unroll
    for (int i = 0; i < 4; ++i) {
        int m = m0 + ty * 4 + i;
        int s = m % SEQ;
        int n = n0 + tx * 4;
        float4 v;
        v.x = gelu_exact(acc[i][0]) + pos[(size_t)s * D + n + 0];
        v.y = gelu_exact(acc[i][1]) + pos[(size_t)s * D + n + 1];
        v.z = gelu_exact(acc[i][2]) + pos[(size_t)s * D + n + 2];
        v.w = gelu_exact(acc[i][3]) + pos[(size_t)s * D + n + 3];
        *(float4*)&x[(size_t)m * D + n] = v;
    }
}

// ---------------------------------------------------------------------------
// Kernel 2: per-row mean / rstd (LayerNorm stats). One wave per row.
// ---------------------------------------------------------------------------
__global__ __launch_bounds__(64) void row_stats(
    const float* __restrict__ x, float* __restrict__ st)
{
    const int m = blockIdx.x;
    const int t = threadIdx.x;
    const float* r = x + (size_t)m * D;
    float s = 0.f, q = 0.f;
    #pragma unroll
    for (int i = 0; i < 4; ++i) {
        float v = r[t + 64 * i];
        s += v;
        q += v * v;
    }
    #pragma unroll
    for (int o = 32; o > 0; o >>= 1) {
        s += __shfl_down(s, o);
        q += __shfl_down(q, o);
    }
    if (t == 0) {
        float mu = s * (1.f / 256.f);
        float var = q * (1.f / 256.f) - mu * mu;
        st[2 * m]     = mu;
        st[2 * m + 1] = rsqrtf(var + 1e-5f);
    }
}

// ---------------------------------------------------------------------------
// Kernel 3: fused LN + input-projection GEMM
// ---------------------------------------------------------------------------
__global__ __launch_bounds__(256) void ln_xp_gemm(
    const float* __restrict__ x, const float* __restrict__ st,
    const float* __restrict__ lnsc, const float* __restrict__ lnbi,
    const float* __restrict__ wih, const float* __restrict__ bih,
    float* __restrict__ xp)
{
    __shared__ float As[64][33];
    __shared__ float Bs[32][65];
    __shared__ float sc[D], bi[D];
    const int m0 = blockIdx.x * 64;
    const int n0 = blockIdx.y * 64;
    const int tid = threadIdx.x;
    const int tx = tid & 15;
    const int ty = tid >> 4;
    sc[tid] = lnsc[tid];
    bi[tid] = lnbi[tid];
    float acc[4][4] = {};

    for (int kc = 0; kc < D; kc += 32) {
        for (int p = 0; p < 8; ++p) {
            int mr = p * 8 + (tid >> 5);
            int kk = tid & 31;
            int m = m0 + mr;
            float mu = st[2 * m], rs = st[2 * m + 1];
            float v = x[(size_t)m * D + kc + kk];
            As[mr][kk] = (v - mu) * rs * sc[kc + kk] + bi[kc + kk];
        }
        for (int p = 0; p < 8; ++p) {
            int nr = p * 8 + (tid >> 5);
            int kk = tid & 31;
            Bs[kk][nr] = wih[(size_t)(n0 + nr) * D + kc + kk];
        }
        __syncthreads();
        #pragma unroll
        for (int kk = 0; kk < 32; ++kk) {
            float a[4], bb[4];
            #pragma unroll
            for (int i = 0; i < 4; ++i) a[i] = As[ty * 4 + i][kk];
            #pragma unroll
            for (int j = 0; j < 4; ++j) bb[j] = Bs[kk][tx * 4 + j];
            #pragma unroll
            for (int i = 0; i < 4; ++i)
                #pragma unroll
                for (int j = 0; j < 4; ++j)
                    acc[i][j] = fmaf(a[i], bb[j], acc[i][j]);
        }
        __syncthreads();
    }
    #pragma unroll
    for (int i = 0; i < 4; ++i) {
        int m = m0 + ty * 4 + i;
        int n = n0 + tx * 4;
        float4 v;
        v.x = acc[i][0] + bih[n + 0];
        v.y = acc[i][1] + bih[n + 1];
        v.z = acc[i][2] + bih[n + 2];
        v.w = acc[i][3] + bih[n + 3];
        *(float4*)&xp[(size_t)m * G3 + n] = v;
    }
}

// ---------------------------------------------------------------------------
// Kernel 4: pack w_hh fp32 -> fp16 pairs: word [kh][s][d] (u32 = 2 fp16),
// s = gate*64 + j covers k = kh*128 + 2j, 2j+1 for output dim d.
// This IS the v_dot2 A-operand layout (k-pair packed).
// ---------------------------------------------------------------------------
__global__ __launch_bounds__(256) void pack_whh(
    const float* __restrict__ whh, unsigned int* __restrict__ wh16)
{
    const int b  = blockIdx.x;        // 0..383
    const int kh = b / 192;
    const int s  = b % 192;
    const int gi = s / 64;            // gate 0=r 1=z 2=n
    const int j  = s % 64;            // k-pair index
    const int d  = threadIdx.x;       // output dim
    const size_t row = (size_t)(gi * D + d) * D + kh * 128 + 2 * j;
    unsigned short lo = __builtin_bit_cast(unsigned short, (_Float16)whh[row]);
    unsigned short hi = __builtin_bit_cast(unsigned short, (_Float16)whh[row + 1]);
    wh16[(size_t)(kh * 192 + s) * 256 + d] = (unsigned int)lo | ((unsigned int)hi << 16);
}

// ---------------------------------------------------------------------------
// Kernel 5: GRU recurrence — SINGLE block per batch, register-resident fp16
// weights consumed by v_dot2_f32_f16 (2 MACs/instruction).
//
// Round-12 post-mortem: fma_mix fixed the scratch disaster (passed, 2.16us/
// step) but VGPR_Count=116 showed the 192 containers parked in AGPRs; each
// asm "v" use forces a v_accvgpr_read -> ~770 VALU inst/step -> 5180cy.
// v_dot2_f32_f16 consumes a WHOLE container word per instruction: worst
// case 1 move + 1 dot2 per container = 384 inst/step (halved), floor 768cy
// if moves are absent. h is packed to fp16 pairs once per step (even lanes
// pack (h[d],h[d+1]) via intra-wave shfl, no extra barrier); h STATE stays
// fp32 in h_lds (z*h and residual exact) — only W*h products see fp16 h
// (added err ~2.5e-4 on gates, vs 1.5-1.7e-3 already-passing w-quant).
// Structure = proven khalf split + LDS reduce; 2 bar_lds/step; no atomics.
// ---------------------------------------------------------------------------
__global__ __launch_bounds__(512, 1) void gru_scan_regs(
    const float* __restrict__ xp, const unsigned int* __restrict__ wh16,
    const float* __restrict__ bhh, float* __restrict__ x)
{
    __shared__ float h_lds[D];                       // fp32 h(t)
    __shared__ __align__(16) unsigned int h16_lds[D / 2];  // packed fp16 pairs
    __shared__ float pr[3][D];                       // khalf1 partials
    const int tid   = threadIdx.x;
    const int d     = tid & 255;
    const int khalf = tid >> 8;         // 0 or 1 (wave-uniform)
    const int batch = blockIdx.x;

    // --- resident weights: 6 x 32 float-containers (= 384 fp16), coalesced -
    // gate g, pair j (k = khalf*128 + 2j, 2j+1): j<32 -> A[j], j>=32 -> B[j-32]
    float wrA[32], wrB[32], wzA[32], wzB[32], wnA[32], wnB[32];
    {
        const unsigned int* wb = wh16 + (size_t)khalf * 192 * 256 + d;
        #pragma unroll
        for (int j = 0; j < 32; ++j) wrA[j] = __uint_as_float(wb[(size_t)(0 * 64 + j) * 256]);
        #pragma unroll
        for (int j = 0; j < 32; ++j) wrB[j] = __uint_as_float(wb[(size_t)(0 * 64 + 32 + j) * 256]);
        #pragma unroll
        for (int j = 0; j < 32; ++j) wzA[j] = __uint_as_float(wb[(size_t)(1 * 64 + j) * 256]);
        #pragma unroll
        for (int j = 0; j < 32; ++j) wzB[j] = __uint_as_float(wb[(size_t)(1 * 64 + 32 + j) * 256]);
        #pragma unroll
        for (int j = 0; j < 32; ++j) wnA[j] = __uint_as_float(wb[(size_t)(2 * 64 + j) * 256]);
        #pragma unroll
        for (int j = 0; j < 32; ++j) wnB[j] = __uint_as_float(wb[(size_t)(2 * 64 + 32 + j) * 256]);
    }
    const float bh_r = bhh[d];
    const float bh_z = bhh[D + d];
    const float bh_n = bhh[2 * D + d];

    const float* xpb = xp + (size_t)batch * SEQ * G3;
    float* xb = x + (size_t)batch * SEQ * D;

    if (tid < D) h_lds[tid] = 0.f;
    if (tid < D / 2) h16_lds[tid] = 0u;
    __syncthreads();

    const unsigned int* hp_base = &h16_lds[khalf * 64];  // this khalf's 64 pairs
    for (int t = 0; t < SEQ; ++t) {
        // issue xp + residual loads early; latency hides under the DOT phase
        float xr = 0.f, xz = 0.f, xn_ = 0.f, xold = 0.f;
        if (khalf == 0) {
            const float* xpt = xpb + (size_t)t * G3;
            xr   = xpt[d];
            xz   = xpt[D + d];
            xn_  = xpt[2 * D + d];
            xold = xb[(size_t)t * D + d];
        }

        // --- DOT phase: 192 v_dot2_f32_f16 against resident packed fp16 ----
        float ar = 0.f, az = 0.f, an = 0.f;
        #pragma unroll
        for (int c = 0; c < 8; ++c) {          // pairs j = 4c .. 4c+3 (A half)
            uint4 hp = *(const uint4*)(hp_base + 4 * c);
            DOT(ar, wrA[4*c+0], hp.x); DOT(ar, wrA[4*c+1], hp.y);
            DOT(ar, wrA[4*c+2], hp.z); DOT(ar, wrA[4*c+3], hp.w);
            DOT(az, wzA[4*c+0], hp.x); DOT(az, wzA[4*c+1], hp.y);
            DOT(az, wzA[4*c+2], hp.z); DOT(az, wzA[4*c+3], hp.w);
            DOT(an, wnA[4*c+0], hp.x); DOT(an, wnA[4*c+1], hp.y);
            DOT(an, wnA[4*c+2], hp.z); DOT(an, wnA[4*c+3], hp.w);
        }
        #pragma unroll
        for (int c = 0; c < 8; ++c) {          // pairs j = 32+4c .. (B half)
            uint4 hp = *(const uint4*)(hp_base + 32 + 4 * c);
            DOT(ar, wrB[4*c+0], hp.x); DOT(ar, wrB[4*c+1], hp.y);
            DOT(ar, wrB[4*c+2], hp.z); DOT(ar, wrB[4*c+3], hp.w);
            DOT(az, wzB[4*c+0], hp.x); DOT(az, wzB[4*c+1], hp.y);
            DOT(az, wzB[4*c+2], hp.z); DOT(az, wzB[4*c+3], hp.w);
            DOT(an, wnB[4*c+0], hp.x); DOT(an, wnB[4*c+1], hp.y);
            DOT(an, wnB[4*c+2], hp.z); DOT(an, wnB[4*c+3], hp.w);
        }
        if (khalf) { pr[0][d] = ar; pr[1][d] = az; pr[2][d] = an; }
        bar_lds();

        // --- finalize: combine (own lo-K + peer hi-K), gates, update -------
        if (khalf == 0) {
            float gr = xr + ar + pr[0][d] + bh_r;
            float gz = xz + az + pr[1][d] + bh_z;
            float gn =      an + pr[2][d] + bh_n;
            float r = 1.f / (1.f + expf(-gr));
            float z = 1.f / (1.f + expf(-gz));
            float n = tanhf(xn_ + r * gn);
            float hnew = (1.f - z) * n + z * h_lds[d];
            h_lds[d] = hnew;
            // pack (h[d], h[d+1]) -> fp16 pair; neighbors are adjacent lanes
            float hn1 = __shfl_down(hnew, 1);
            if (!(d & 1)) {
                unsigned short l0 = __builtin_bit_cast(unsigned short, (_Float16)hnew);
                unsigned short l1 = __builtin_bit_cast(unsigned short, (_Float16)hn1);
                h16_lds[d >> 1] = (unsigned int)l0 | ((unsigned int)l1 << 16);
            }
            xb[(size_t)t * D + d] = xold + hnew;
        }
        bar_lds();
    }
}

// ---------------------------------------------------------------------------
// Kernel 6: final LN + mean-pool over sequence
// ---------------------------------------------------------------------------
__global__ __launch_bounds__(256) void pool_ln(
    const float* __restrict__ x, const float* __restrict__ st,
    const float* __restrict__ fsc, const float* __restrict__ fbi,
    float* __restrict__ emb)
{
    const int b = blockIdx.x;
    const int d = threadIdx.x;
    float acc = 0.f;
    for (int s = 0; s < SEQ; ++s) {
        int m = b * SEQ + s;
        acc += (x[(size_t)m * D + d] - st[2 * m]) * st[2 * m + 1];
    }
    emb[b * D + d] = (acc * (1.f / (float)SEQ)) * fsc[d] + fbi[d];
}

// ---------------------------------------------------------------------------
// Kernel 7: classification head (tiny). Single block.
// ---------------------------------------------------------------------------
__global__ __launch_bounds__(256) void head_mlp(
    const float* __restrict__ emb, const float* __restrict__ w1,
    const float* __restrict__ b1, const float* __restrict__ w2,
    const float* __restrict__ b2, float* __restrict__ out)
{
    __shared__ float es[NB][D + 1];
    __shared__ float h1[NB][128 + 1];
    const int t = threadIdx.x;
    for (int i = t; i < NB * D; i += 256) es[i / D][i % D] = emb[i];
    __syncthreads();
    for (int i = t; i < NB * 128; i += 256) {
        int bb = i / 128, j = i % 128;
        float a = b1[j];
        for (int k = 0; k < D; ++k) a = fmaf(es[bb][k], w1[(size_t)k * 128 + j], a);
        h1[bb][j] = gelu_exact(a);
    }
    __syncthreads();
    for (int i = t; i < NB * 8; i += 256) {
        int bb = i / 8, c = i % 8;
        float a = b2[c];
        for (int k = 0; k < 128; ++k) a = fmaf(h1[bb][k], w2[(size_t)k * 8 + c], a);
        out[i] = a;
    }
}

// ---------------------------------------------------------------------------
extern "C" void kernel_launch(void* const* d_in, const int* in_sizes, int n_in,
                              void* d_out, int out_size, void* d_ws, size_t ws_size,
                              hipStream_t stream)
{
    const float* wav  = (const float*)d_in[0];
    const float* cw   = (const float*)d_in[1];
    const float* pos  = (const float*)d_in[2];
    const float* lnsc = (const float*)d_in[3];
    const float* lnbi = (const float*)d_in[4];
    const float* wih  = (const float*)d_in[5];
    const float* whh  = (const float*)d_in[6];
    const float* bih  = (const float*)d_in[7];
    const float* bhh  = (const float*)d_in[8];
    const float* fsc  = (const float*)d_in[9];
    const float* fbi  = (const float*)d_in[10];
    const float* hw1  = (const float*)d_in[11];
    const float* hb1  = (const float*)d_in[12];
    const float* hw2  = (const float*)d_in[13];
    const float* hb2  = (const float*)d_in[14];

    float* ws    = (float*)d_ws;
    float* x     = ws;                        // 8,192,000 f
    float* xp    = x + (size_t)M_TOTAL * D;   // 24,576,000 f
    float* st    = xp + (size_t)M_TOTAL * G3; // 64,000 f
    unsigned int* wh16 = (unsigned int*)(st + 2 * M_TOTAL); // 98,304 u32
    float* emb   = (float*)(wh16 + 98304);    // 8,192 f

    conv_gelu_pos<<<dim3(M_TOTAL / 64, D / 64), 256, 0, stream>>>(wav, cw, pos, x);

    for (int l = 0; l < NL; ++l) {
        row_stats<<<M_TOTAL, 64, 0, stream>>>(x, st);
        ln_xp_gemm<<<dim3(M_TOTAL / 64, G3 / 64), 256, 0, stream>>>(
            x, st, lnsc + (size_t)l * D, lnbi + (size_t)l * D,
            wih + (size_t)l * G3 * D, bih + (size_t)l * G3, xp);
        pack_whh<<<384, 256, 0, stream>>>(whh + (size_t)l * G3 * D, wh16);
        gru_scan_regs<<<NB, 512, 0, stream>>>(
            xp, wh16, bhh + (size_t)l * G3, x);
    }

    row_stats<<<M_TOTAL, 64, 0, stream>>>(x, st);
    pool_ln<<<NB, D, 0, stream>>>(x, st, fsc, fbi, emb);
    head_mlp<<<1, 256, 0, stream>>>(emb, hw1, hb1, hw2, hb2, (float*)d_out);
}